// Round 1
// baseline (413.330 us; speedup 1.0000x reference)
//
#include <hip/hip_runtime.h>
#include <hip/hip_bf16.h>

#define B_  16
#define E_  8192
#define NN_ 384
#define N1_ 385
#define H_  32
#define PLANE_ (N1_ * N1_)   // 148225
#define TOTAL_ (B_ * H_ * PLANE_)  // 75,891,200

// ---------------------------------------------------------------------------
// Kernel 1: initialize output.
// out[b][h][i][j] = virtual_w[h] if (i==0 || j==0) else 0.
// Valid edges always scatter to indices >= 1, so row 0 / col 0 receive ONLY
// the virtual-token term; everything else starts at 0 and gets atomics.
// ---------------------------------------------------------------------------
__global__ __launch_bounds__(256) void init_out_kernel(
    float* __restrict__ out, const float* __restrict__ virtual_w)
{
    unsigned int tid = blockIdx.x * blockDim.x + threadIdx.x;
    unsigned int base = tid * 4u;
    if (base >= (unsigned int)TOTAL_) return;

    float4 v;
    float* pv = &v.x;
#pragma unroll
    for (int u = 0; u < 4; ++u) {
        unsigned int idx = base + u;               // fits in 32 bits (75.9M)
        unsigned int bh     = idx / (unsigned int)PLANE_;   // magic-mul
        unsigned int within = idx - bh * (unsigned int)PLANE_;
        unsigned int h = bh & (H_ - 1);
        unsigned int i = within / (unsigned int)N1_;        // magic-mul
        unsigned int j = within - i * (unsigned int)N1_;
        pv[u] = (i == 0u || j == 0u) ? virtual_w[h] : 0.0f;
    }
    *reinterpret_cast<float4*>(out + base) = v;
}

// ---------------------------------------------------------------------------
// Kernel 2: per-edge embedding + MLP + symmetric atomic scatter.
// One thread per (b, e). Weights/tables staged in LDS (broadcast reads).
// ---------------------------------------------------------------------------
__global__ __launch_bounds__(256) void edge_kernel(
    const float4* __restrict__ edge_feat,    // (B,E,4)
    const int*    __restrict__ edge_index,   // (B,2,E)
    const void*   __restrict__ edge_mask,    // (B,E) bool(1B) or int32 — detected
    const int*    __restrict__ nlig,         // (B,)
    const float*  __restrict__ structural_w, // (20,H)
    const float*  __restrict__ plip_protein_w, // (15,H)
    const float*  __restrict__ plip_ligand_w,  // (15,H)
    const float*  __restrict__ plip_inter_w,   // (15,H)
    const float*  __restrict__ loc_w,        // (4,H)
    const float*  __restrict__ W1,           // (H,1)
    const float*  __restrict__ b1,           // (H,)
    const float*  __restrict__ W2,           // (H,H)
    const float*  __restrict__ b2,           // (H,)
    float* __restrict__ out)                 // (B,H,385,385)
{
    __shared__ float sW2[H_ * H_];
    __shared__ float sW1[H_], sb1[H_], sb2[H_];
    __shared__ float sStruct[20 * H_];
    __shared__ float sPlipP[15 * H_], sPlipL[15 * H_], sPlipI[15 * H_];
    __shared__ float sLoc[4 * H_];

    for (int i = threadIdx.x; i < H_ * H_; i += blockDim.x) sW2[i] = W2[i];
    if (threadIdx.x < H_) {
        sW1[threadIdx.x] = W1[threadIdx.x];
        sb1[threadIdx.x] = b1[threadIdx.x];
        sb2[threadIdx.x] = b2[threadIdx.x];
    }
    for (int i = threadIdx.x; i < 20 * H_; i += blockDim.x) sStruct[i] = structural_w[i];
    for (int i = threadIdx.x; i < 15 * H_; i += blockDim.x) {
        sPlipP[i] = plip_protein_w[i];
        sPlipL[i] = plip_ligand_w[i];
        sPlipI[i] = plip_inter_w[i];
    }
    for (int i = threadIdx.x; i < 4 * H_; i += blockDim.x) sLoc[i] = loc_w[i];

    // Detect mask layout (wave-uniform): int32 mask has only {0,1} words;
    // a byte mask (~90% true) yields words like 0x01010101. First 64 words
    // (256 bytes) are in-bounds under either interpretation.
    int lane = threadIdx.x & 63;
    int probe = ((const int*)edge_mask)[lane];
    bool byte_mask = __any(probe != 0 && probe != 1);

    __syncthreads();

    int gid = blockIdx.x * blockDim.x + threadIdx.x;  // exact grid: B*E threads
    int b = gid >> 13;          // / E_
    int e = gid & (E_ - 1);

    bool m = byte_mask ? (((const unsigned char*)edge_mask)[gid] != 0)
                       : (((const int*)edge_mask)[gid] != 0);
    if (!m) return;

    int src = edge_index[(b * 2 + 0) * E_ + e];
    int tgt = edge_index[(b * 2 + 1) * E_ + e];
    // valid = in-bounds; keep excludes the (0,0) placeholder edge
    if (src < 0 || src >= NN_ || tgt < 0 || tgt >= NN_) return;
    if (src == 0 && tgt == 0) return;

    float4 ef = edge_feat[gid];
    int c0 = (int)ef.x, c1 = (int)ef.y, c2 = (int)ef.z;
    float dist = ef.w;

    const float* type_ptr = nullptr;
    const float* loc_ptr  = nullptr;
    if (c0 == 0 || c0 == 1) {
        int si = c0 * 4 + c1 * 2 + c2;
        si = min(max(si, 0), 19);
        type_ptr = &sStruct[si * H_];
    } else if (c0 == 5) {
        int pi = min(max(c1, 0), 14);
        int nl = nlig[b];
        bool sl = src < nl, tl = tgt < nl;
        const float* pw;
        int loc;
        if (sl && tl)        { pw = sPlipL; loc = 0; }
        else if (!sl && !tl) { pw = sPlipP; loc = 1; }
        else                 { pw = sPlipI; loc = 2; }
        type_ptr = &pw[pi * H_];
        loc_ptr  = &sLoc[loc * H_];
    }

    // hidden layer: hk[k] = relu(dist*W1[k] + b1[k])
    float hk[H_];
#pragma unroll
    for (int k = 0; k < H_; ++k) {
        float v = fmaf(dist, sW1[k], sb1[k]);
        hk[k] = v > 0.0f ? v : 0.0f;
    }

    int s1 = src + 1, t1 = tgt + 1;
    float* outb = out + (size_t)b * H_ * PLANE_;
    int off1 = s1 * N1_ + t1;
    int off2 = t1 * N1_ + s1;

#pragma unroll 4
    for (int h = 0; h < H_; ++h) {
        float acc = sb2[h];
#pragma unroll
        for (int k = 0; k < H_; ++k) acc = fmaf(hk[k], sW2[h * H_ + k], acc);
        if (type_ptr) acc += type_ptr[h];
        if (loc_ptr)  acc += loc_ptr[h];
        float* p = outb + (size_t)h * PLANE_;
        unsafeAtomicAdd(p + off1, acc);   // native global_atomic_add_f32
        unsafeAtomicAdd(p + off2, acc);   // symmetric (t,s); s1==t1 adds twice, matching ref
    }
}

// ---------------------------------------------------------------------------
extern "C" void kernel_launch(void* const* d_in, const int* in_sizes, int n_in,
                              void* d_out, int out_size, void* d_ws, size_t ws_size,
                              hipStream_t stream)
{
    const float4* edge_feat      = (const float4*)d_in[0];
    // d_in[1] node_feat: unused by the forward math
    const int*    edge_index     = (const int*)  d_in[2];
    const void*   edge_mask      =               d_in[3];
    const int*    nlig           = (const int*)  d_in[4];
    const float*  structural_w   = (const float*)d_in[5];
    const float*  plip_protein_w = (const float*)d_in[6];
    const float*  plip_ligand_w  = (const float*)d_in[7];
    const float*  plip_inter_w   = (const float*)d_in[8];
    const float*  loc_w          = (const float*)d_in[9];
    const float*  virtual_w      = (const float*)d_in[10];
    const float*  W1             = (const float*)d_in[11];
    const float*  b1             = (const float*)d_in[12];
    const float*  W2             = (const float*)d_in[13];
    const float*  b2             = (const float*)d_in[14];
    float* out = (float*)d_out;

    unsigned int nth  = (unsigned int)(TOTAL_ / 4);          // 18,972,800 (TOTAL_ % 4 == 0)
    unsigned int nblk = (nth + 255u) / 256u;
    init_out_kernel<<<nblk, 256, 0, stream>>>(out, virtual_w);

    edge_kernel<<<(B_ * E_) / 256, 256, 0, stream>>>(
        edge_feat, edge_index, edge_mask, nlig,
        structural_w, plip_protein_w, plip_ligand_w, plip_inter_w,
        loc_w, W1, b1, W2, b2, out);
}

// Round 2
// 191.410 us; speedup vs baseline: 2.1594x; 2.1594x over previous
//
#include <hip/hip_runtime.h>
#include <hip/hip_bf16.h>

#define B_  16
#define E_  8192
#define NN_ 384
#define N1_ 385
#define H_  32
#define PLANE_ (N1_ * N1_)          // 148225
#define TOTAL_ (B_ * H_ * PLANE_)   // 75,891,200
#define CAP_ 128                    // bin capacity; Poisson(38) -> P(>128) ~ 1e-30
#define NBIN_ (B_ * N1_)            // 6160 bins, keyed by (b, row_index_1based)

// ============================================================================
// FAST PATH: bin edges by row, then one workgroup per output row gathers.
// ============================================================================

__global__ __launch_bounds__(256) void zero_counts_kernel(int* __restrict__ counts)
{
    int i = blockIdx.x * blockDim.x + threadIdx.x;
    if (i < NBIN_) counts[i] = 0;
}

__global__ __launch_bounds__(256) void bin_kernel(
    const int*  __restrict__ edge_index,   // (B,2,E)
    const void* __restrict__ edge_mask,    // (B,E) bool(1B) or int32 — detected
    int* __restrict__ counts,              // (NBIN_)
    int* __restrict__ bins)                // (NBIN_, CAP_)
{
    // Detect mask layout (wave-uniform): int32 mask has only {0,1} words;
    // a byte mask (~90% true) yields words like 0x01010101.
    int lane = threadIdx.x & 63;
    int probe = ((const int*)edge_mask)[lane];
    bool byte_mask = __any(probe != 0 && probe != 1);

    int gid = blockIdx.x * blockDim.x + threadIdx.x;   // exact grid: B*E
    int b = gid >> 13;
    int e = gid & (E_ - 1);

    bool m = byte_mask ? (((const unsigned char*)edge_mask)[gid] != 0)
                       : (((const int*)edge_mask)[gid] != 0);
    if (!m) return;

    int src = edge_index[(b * 2 + 0) * E_ + e];
    int tgt = edge_index[(b * 2 + 1) * E_ + e];
    if (src < 0 || src >= NN_ || tgt < 0 || tgt >= NN_) return;
    if (src == 0 && tgt == 0) return;

    int s1 = src + 1, t1 = tgt + 1;
    // flag 0: entry lives in row s1 (other = t1); flag 1: row t1 (other = s1).
    int p = atomicAdd(&counts[b * N1_ + s1], 1);
    if (p < CAP_) bins[(b * N1_ + s1) * CAP_ + p] = (gid << 1);
    p = atomicAdd(&counts[b * N1_ + t1], 1);
    if (p < CAP_) bins[(b * N1_ + t1) * CAP_ + p] = (gid << 1) | 1;
}

// One workgroup per (b, i) output row. Accumulate H x N1 row in LDS, write once.
__global__ __launch_bounds__(256) void row_kernel(
    const float4* __restrict__ edge_feat,      // (B,E,4)
    const int*    __restrict__ edge_index,     // (B,2,E)
    const int*    __restrict__ nlig,           // (B,)
    const float*  __restrict__ structural_w,   // (20,H)
    const float*  __restrict__ plip_protein_w, // (15,H)
    const float*  __restrict__ plip_ligand_w,  // (15,H)
    const float*  __restrict__ plip_inter_w,   // (15,H)
    const float*  __restrict__ loc_w,          // (4,H)
    const float*  __restrict__ virtual_w,      // (1,H)
    const float*  __restrict__ W1,             // (H,1)
    const float*  __restrict__ b1,             // (H,)
    const float*  __restrict__ W2,             // (H,H)
    const float*  __restrict__ b2,             // (H,)
    const int*    __restrict__ counts,         // (NBIN_)
    const int*    __restrict__ bins,           // (NBIN_, CAP_)
    float* __restrict__ out)                   // (B,H,N1,N1)
{
    __shared__ float srow[H_ * N1_];   // srow[h*385 + t]  (385 odd -> conflict-free)
    __shared__ float sW2T[H_ * H_];    // transposed: sW2T[k*H + h] = W2[h][k]
    __shared__ float sW1[H_], sb1[H_], sb2[H_], sLoc[4 * H_];

    int bid = blockIdx.x;              // 0 .. B*N1-1
    int b = bid / N1_;
    int i = bid - b * N1_;             // row index (0 = virtual row)
    int tid = threadIdx.x;

    // stage small tables (W2 transposed so lane-h reads are bank-conflict-free)
    for (int idx = tid; idx < H_ * H_; idx += 256) {
        int h = idx >> 5, k = idx & 31;
        sW2T[k * H_ + h] = W2[idx];
    }
    if (tid < H_) { sW1[tid] = W1[tid]; sb1[tid] = b1[tid]; sb2[tid] = b2[tid]; }
    for (int idx = tid; idx < 4 * H_; idx += 256) sLoc[idx] = loc_w[idx];

    // init row: virtual token at (i==0 row everywhere) and (t==0 column)
    for (int idx = tid; idx < H_ * N1_; idx += 256) {
        int h = idx / N1_;
        int t = idx - h * N1_;
        srow[idx] = (i == 0 || t == 0) ? virtual_w[h] : 0.0f;
    }
    __syncthreads();

    int cnt = counts[bid];
    cnt = cnt < CAP_ ? cnt : CAP_;     // i==0 bin is never written -> cnt 0

    int grp = tid >> 5;                // 8 groups of 32 lanes; lane = h
    int h = tid & 31;
    for (int j = grp; j < cnt; j += 8) {
        int entry = bins[bid * CAP_ + j];
        int gid  = entry >> 1;
        int flag = entry & 1;
        int e = gid & (E_ - 1);

        int src = edge_index[(b * 2 + 0) * E_ + e];
        int tgt = edge_index[(b * 2 + 1) * E_ + e];
        float4 ef = edge_feat[gid];
        int c0 = (int)ef.x, c1 = (int)ef.y, c2 = (int)ef.z;
        float dist = ef.w;

        // dist MLP, lane h computes output channel h
        float acc = sb2[h];
#pragma unroll
        for (int k = 0; k < H_; ++k) {
            float v = fmaf(dist, sW1[k], sb1[k]);
            v = v > 0.0f ? v : 0.0f;
            acc = fmaf(v, sW2T[k * H_ + h], acc);
        }

        // type embedding
        if (c0 == 0 || c0 == 1) {
            int si = c0 * 4 + c1 * 2 + c2;
            si = min(max(si, 0), 19);
            acc += structural_w[si * H_ + h];
        } else if (c0 == 5) {
            int pi = min(max(c1, 0), 14);
            int nl = nlig[b];
            bool sl = src < nl, tl = tgt < nl;
            const float* pw;
            int loc;
            if (sl && tl)        { pw = plip_ligand_w;  loc = 0; }
            else if (!sl && !tl) { pw = plip_protein_w; loc = 1; }
            else                 { pw = plip_inter_w;   loc = 2; }
            acc += pw[pi * H_ + h] + sLoc[loc * H_ + h];
        }

        int other = flag ? (src + 1) : (tgt + 1);
        atomicAdd(&srow[h * N1_ + other], acc);   // banks (h+other)%32: conflict-free
    }
    __syncthreads();

    // single coalesced write of the whole row block: out[b, h, i, 0:385]
    float* outbi = out + ((size_t)b * H_) * PLANE_ + (size_t)i * N1_;
    for (int idx = tid; idx < H_ * N1_; idx += 256) {
        int h = idx / N1_;
        int t = idx - h * N1_;
        outbi[(size_t)h * PLANE_ + t] = srow[idx];
    }
}

// ============================================================================
// FALLBACK PATH (round-1, passing): used only if ws_size is too small.
// ============================================================================

__global__ __launch_bounds__(256) void init_out_kernel(
    float* __restrict__ out, const float* __restrict__ virtual_w)
{
    unsigned int tid = blockIdx.x * blockDim.x + threadIdx.x;
    unsigned int base = tid * 4u;
    if (base >= (unsigned int)TOTAL_) return;
    float4 v; float* pv = &v.x;
#pragma unroll
    for (int u = 0; u < 4; ++u) {
        unsigned int idx = base + u;
        unsigned int bh     = idx / (unsigned int)PLANE_;
        unsigned int within = idx - bh * (unsigned int)PLANE_;
        unsigned int h = bh & (H_ - 1);
        unsigned int i = within / (unsigned int)N1_;
        unsigned int j = within - i * (unsigned int)N1_;
        pv[u] = (i == 0u || j == 0u) ? virtual_w[h] : 0.0f;
    }
    *reinterpret_cast<float4*>(out + base) = v;
}

__global__ __launch_bounds__(256) void edge_kernel(
    const float4* __restrict__ edge_feat, const int* __restrict__ edge_index,
    const void* __restrict__ edge_mask, const int* __restrict__ nlig,
    const float* __restrict__ structural_w, const float* __restrict__ plip_protein_w,
    const float* __restrict__ plip_ligand_w, const float* __restrict__ plip_inter_w,
    const float* __restrict__ loc_w, const float* __restrict__ W1,
    const float* __restrict__ b1, const float* __restrict__ W2,
    const float* __restrict__ b2, float* __restrict__ out)
{
    __shared__ float sW2[H_ * H_];
    __shared__ float sW1[H_], sb1[H_], sb2[H_];
    __shared__ float sStruct[20 * H_];
    __shared__ float sPlipP[15 * H_], sPlipL[15 * H_], sPlipI[15 * H_];
    __shared__ float sLoc[4 * H_];

    for (int i = threadIdx.x; i < H_ * H_; i += blockDim.x) sW2[i] = W2[i];
    if (threadIdx.x < H_) {
        sW1[threadIdx.x] = W1[threadIdx.x];
        sb1[threadIdx.x] = b1[threadIdx.x];
        sb2[threadIdx.x] = b2[threadIdx.x];
    }
    for (int i = threadIdx.x; i < 20 * H_; i += blockDim.x) sStruct[i] = structural_w[i];
    for (int i = threadIdx.x; i < 15 * H_; i += blockDim.x) {
        sPlipP[i] = plip_protein_w[i]; sPlipL[i] = plip_ligand_w[i]; sPlipI[i] = plip_inter_w[i];
    }
    for (int i = threadIdx.x; i < 4 * H_; i += blockDim.x) sLoc[i] = loc_w[i];

    int lane = threadIdx.x & 63;
    int probe = ((const int*)edge_mask)[lane];
    bool byte_mask = __any(probe != 0 && probe != 1);
    __syncthreads();

    int gid = blockIdx.x * blockDim.x + threadIdx.x;
    int b = gid >> 13, e = gid & (E_ - 1);
    bool m = byte_mask ? (((const unsigned char*)edge_mask)[gid] != 0)
                       : (((const int*)edge_mask)[gid] != 0);
    if (!m) return;
    int src = edge_index[(b * 2 + 0) * E_ + e];
    int tgt = edge_index[(b * 2 + 1) * E_ + e];
    if (src < 0 || src >= NN_ || tgt < 0 || tgt >= NN_) return;
    if (src == 0 && tgt == 0) return;

    float4 ef = edge_feat[gid];
    int c0 = (int)ef.x, c1 = (int)ef.y, c2 = (int)ef.z;
    float dist = ef.w;
    const float* type_ptr = nullptr; const float* loc_ptr = nullptr;
    if (c0 == 0 || c0 == 1) {
        int si = min(max(c0 * 4 + c1 * 2 + c2, 0), 19);
        type_ptr = &sStruct[si * H_];
    } else if (c0 == 5) {
        int pi = min(max(c1, 0), 14);
        int nl = nlig[b];
        bool sl = src < nl, tl = tgt < nl;
        const float* pw; int loc;
        if (sl && tl)        { pw = sPlipL; loc = 0; }
        else if (!sl && !tl) { pw = sPlipP; loc = 1; }
        else                 { pw = sPlipI; loc = 2; }
        type_ptr = &pw[pi * H_]; loc_ptr = &sLoc[loc * H_];
    }
    float hk[H_];
#pragma unroll
    for (int k = 0; k < H_; ++k) {
        float v = fmaf(dist, sW1[k], sb1[k]);
        hk[k] = v > 0.0f ? v : 0.0f;
    }
    int s1 = src + 1, t1 = tgt + 1;
    float* outb = out + (size_t)b * H_ * PLANE_;
    int off1 = s1 * N1_ + t1, off2 = t1 * N1_ + s1;
#pragma unroll 4
    for (int h = 0; h < H_; ++h) {
        float acc = sb2[h];
#pragma unroll
        for (int k = 0; k < H_; ++k) acc = fmaf(hk[k], sW2[h * H_ + k], acc);
        if (type_ptr) acc += type_ptr[h];
        if (loc_ptr)  acc += loc_ptr[h];
        float* p = outb + (size_t)h * PLANE_;
        unsafeAtomicAdd(p + off1, acc);
        unsafeAtomicAdd(p + off2, acc);
    }
}

// ============================================================================
extern "C" void kernel_launch(void* const* d_in, const int* in_sizes, int n_in,
                              void* d_out, int out_size, void* d_ws, size_t ws_size,
                              hipStream_t stream)
{
    const float4* edge_feat      = (const float4*)d_in[0];
    const int*    edge_index     = (const int*)  d_in[2];
    const void*   edge_mask      =               d_in[3];
    const int*    nlig           = (const int*)  d_in[4];
    const float*  structural_w   = (const float*)d_in[5];
    const float*  plip_protein_w = (const float*)d_in[6];
    const float*  plip_ligand_w  = (const float*)d_in[7];
    const float*  plip_inter_w   = (const float*)d_in[8];
    const float*  loc_w          = (const float*)d_in[9];
    const float*  virtual_w      = (const float*)d_in[10];
    const float*  W1             = (const float*)d_in[11];
    const float*  b1             = (const float*)d_in[12];
    const float*  W2             = (const float*)d_in[13];
    const float*  b2             = (const float*)d_in[14];
    float* out = (float*)d_out;

    const size_t counts_off = 0;
    const size_t bins_off   = 65536;
    const size_t need = bins_off + (size_t)NBIN_ * CAP_ * sizeof(int);

    if (ws_size >= need) {
        int* counts = (int*)((char*)d_ws + counts_off);
        int* bins   = (int*)((char*)d_ws + bins_off);

        zero_counts_kernel<<<(NBIN_ + 255) / 256, 256, 0, stream>>>(counts);
        bin_kernel<<<(B_ * E_) / 256, 256, 0, stream>>>(edge_index, edge_mask, counts, bins);
        row_kernel<<<B_ * N1_, 256, 0, stream>>>(
            edge_feat, edge_index, nlig,
            structural_w, plip_protein_w, plip_ligand_w, plip_inter_w,
            loc_w, virtual_w, W1, b1, W2, b2, counts, bins, out);
    } else {
        // fallback: round-1 scatter path
        unsigned int nth  = (unsigned int)(TOTAL_ / 4);
        unsigned int nblk = (nth + 255u) / 256u;
        init_out_kernel<<<nblk, 256, 0, stream>>>(out, virtual_w);
        edge_kernel<<<(B_ * E_) / 256, 256, 0, stream>>>(
            edge_feat, edge_index, edge_mask, nlig,
            structural_w, plip_protein_w, plip_ligand_w, plip_inter_w,
            loc_w, W1, b1, W2, b2, out);
    }
}

// Round 3
// 139.423 us; speedup vs baseline: 2.9646x; 1.3729x over previous
//
#include <hip/hip_runtime.h>
#include <hip/hip_bf16.h>

#define B_  16
#define E_  8192
#define NN_ 384
#define N1_ 385
#define H_  32
#define HH_ 16                      // h per block (half)
#define PLANE_ (N1_ * N1_)          // 148225
#define TOTAL_ (B_ * H_ * PLANE_)   // 75,891,200
#define CAP_ 128                    // bin capacity; Poisson(~38) -> overflow ~never
#define NBIN_ (B_ * N1_)            // 6160 bins keyed by (b, row_index_1based)

// ============================================================================
// FAST PATH
// ============================================================================

__global__ __launch_bounds__(256) void zero_counts_kernel(int* __restrict__ counts)
{
    int i = blockIdx.x * blockDim.x + threadIdx.x;
    if (i < NBIN_) counts[i] = 0;
}

// Pack per-endpoint entry: [loc:2][other:9][gid:17]
__global__ __launch_bounds__(256) void bin_kernel(
    const int*  __restrict__ edge_index,   // (B,2,E)
    const void* __restrict__ edge_mask,    // (B,E) bool(1B) or int32 — detected
    const int*  __restrict__ nlig,         // (B,)
    int* __restrict__ counts,              // (NBIN_)
    int* __restrict__ bins)                // (NBIN_, CAP_)
{
    // Detect mask layout (wave-uniform): int32 mask has only {0,1} words;
    // byte mask (~90% true) yields words like 0x01010101.
    int lane = threadIdx.x & 63;
    int probe = ((const int*)edge_mask)[lane];
    bool byte_mask = __any(probe != 0 && probe != 1);

    int gid = blockIdx.x * blockDim.x + threadIdx.x;   // exact grid: B*E
    int b = gid >> 13;
    int e = gid & (E_ - 1);

    bool m = byte_mask ? (((const unsigned char*)edge_mask)[gid] != 0)
                       : (((const int*)edge_mask)[gid] != 0);
    if (!m) return;

    int src = edge_index[(b * 2 + 0) * E_ + e];
    int tgt = edge_index[(b * 2 + 1) * E_ + e];
    if (src < 0 || src >= NN_ || tgt < 0 || tgt >= NN_) return;
    if (src == 0 && tgt == 0) return;

    int nl = nlig[b];
    bool sl = src < nl, tl = tgt < nl;
    int loc = (sl && tl) ? 0 : ((!sl && !tl) ? 1 : 2);

    int s1 = src + 1, t1 = tgt + 1;
    int base = (loc << 26) | gid;
    int p = atomicAdd(&counts[b * N1_ + s1], 1);
    if (p < CAP_) bins[(b * N1_ + s1) * CAP_ + p] = base | (t1 << 17);
    p = atomicAdd(&counts[b * N1_ + t1], 1);
    if (p < CAP_) bins[(b * N1_ + t1) * CAP_ + p] = base | (s1 << 17);
}

// One workgroup per (b, i, h-half). Accumulate HH_ x N1 in LDS, write once.
__global__ __launch_bounds__(256) void row_kernel(
    const float4* __restrict__ edge_feat,      // (B,E,4)
    const float*  __restrict__ structural_w,   // (20,H)
    const float*  __restrict__ plip_protein_w, // (15,H)
    const float*  __restrict__ plip_ligand_w,  // (15,H)
    const float*  __restrict__ plip_inter_w,   // (15,H)
    const float*  __restrict__ loc_w,          // (4,H)
    const float*  __restrict__ virtual_w,      // (1,H)
    const float*  __restrict__ W1,             // (H,1)
    const float*  __restrict__ b1,             // (H,)
    const float*  __restrict__ W2,             // (H,H)
    const float*  __restrict__ b2,             // (H,)
    const int*    __restrict__ counts,         // (NBIN_)
    const int*    __restrict__ bins,           // (NBIN_, CAP_)
    float* __restrict__ out)                   // (B,H,N1,N1)
{
    __shared__ float srow[HH_ * N1_];   // 24640 B; srow[hh*385 + t]
    __shared__ float sW2T[H_ * HH_];    // sW2T[k*16 + hh] = W2[(h0+hh)*32 + k]
    __shared__ float sW1[H_], sb1[H_];
    __shared__ float sb2h[HH_], sVirt[HH_];
    __shared__ float sLoc[4 * HH_];

    int half  = blockIdx.x & 1;
    int rowid = blockIdx.x >> 1;        // 0 .. B*N1-1
    int b = rowid / N1_;
    int i = rowid - b * N1_;
    int h0 = half * HH_;
    int tid = threadIdx.x;
    int wv = tid >> 6, lane = tid & 63;

    // ---- stage tables ----
    for (int idx = tid; idx < H_ * HH_; idx += 256) {
        int k = idx >> 4, hh = idx & 15;
        sW2T[idx] = W2[(h0 + hh) * H_ + k];
    }
    if (tid < H_) { sW1[tid] = W1[tid]; sb1[tid] = b1[tid]; }
    if (tid < HH_) { sb2h[tid] = b2[h0 + tid]; sVirt[tid] = virtual_w[h0 + tid]; }
    if (tid >= 64 && tid < 64 + 4 * HH_) {
        int idx = tid - 64;                      // loc*16 + hh
        sLoc[idx] = loc_w[(idx >> 4) * H_ + h0 + (idx & 15)];
    }

    // ---- init srow (no divisions): wave wv owns rows hh = wv, wv+4, ... ----
    // i==0: whole row = virtual; else t==0 column = virtual, rest 0.
    for (int hh = wv; hh < HH_; hh += 4) {
        float vw = virtual_w[h0 + hh];
        float fill = (i == 0) ? vw : 0.0f;
        float* r = &srow[hh * N1_];
        for (int t = lane; t < N1_; t += 64) r[t] = fill;
        if (i != 0 && lane == 0) r[0] = vw;
    }
    __syncthreads();

    // ---- edge gather: 16 groups of 16 lanes; lane-in-group = hh ----
    int cnt = counts[rowid];
    cnt = cnt < CAP_ ? cnt : CAP_;
    int grp = tid >> 4;
    int hh  = tid & 15;
    for (int j = grp; j < cnt; j += 16) {
        int entry = bins[rowid * CAP_ + j];
        int gid   = entry & 0x1FFFF;
        int other = (entry >> 17) & 0x1FF;
        int loc   = (entry >> 26) & 3;

        float4 ef = edge_feat[gid];
        int c0 = (int)ef.x, c1 = (int)ef.y, c2 = (int)ef.z;
        float dist = ef.w;

        // dist MLP: lane computes channel h0+hh
        float acc = sb2h[hh];
#pragma unroll
        for (int k = 0; k < H_; ++k) {
            float v = fmaf(dist, sW1[k], sb1[k]);
            v = v > 0.0f ? v : 0.0f;
            acc = fmaf(v, sW2T[k * HH_ + hh], acc);
        }

        if (c0 == 0 || c0 == 1) {
            int si = min(max(c0 * 4 + c1 * 2 + c2, 0), 19);
            acc += structural_w[si * H_ + h0 + hh];
        } else if (c0 == 5) {
            int pi = min(max(c1, 0), 14);
            const float* pw = (loc == 0) ? plip_ligand_w
                            : (loc == 1) ? plip_protein_w : plip_inter_w;
            acc += pw[pi * H_ + h0 + hh] + sLoc[loc * HH_ + hh];
        }

        atomicAdd(&srow[hh * N1_ + other], acc);
    }
    __syncthreads();

    // ---- write-out: wave wv owns rows hh = wv, wv+4, ...; float4 stores ----
    for (int hhw = wv; hhw < HH_; hhw += 4) {
        int h = h0 + hhw;
        const float* r = &srow[hhw * N1_];
        float* dst = out + ((size_t)(b * H_ + h)) * PLANE_ + (size_t)i * N1_;
        // base element index mod 4 == (h + i) & 3  (PLANE_%4==1, N1_%4==1, 32*b%4==0)
        int off = (-(h + i)) & 3;
        if (lane < off) dst[lane] = r[lane];
        int nvec = (N1_ - off) >> 2;            // 95 or 96
        for (int q = lane; q < nvec; q += 64) { // <= 2 iterations
            int t = off + (q << 2);
            float4 v;
            v.x = r[t]; v.y = r[t + 1]; v.z = r[t + 2]; v.w = r[t + 3];
            *reinterpret_cast<float4*>(dst + t) = v;
        }
        int done = off + (nvec << 2);
        int rem = N1_ - done;                   // 0..3
        if (lane < rem) dst[done + lane] = r[done + lane];
    }
}

// ============================================================================
// FALLBACK PATH (round-1, passing): used only if ws_size is too small.
// ============================================================================

__global__ __launch_bounds__(256) void init_out_kernel(
    float* __restrict__ out, const float* __restrict__ virtual_w)
{
    unsigned int tid = blockIdx.x * blockDim.x + threadIdx.x;
    unsigned int base = tid * 4u;
    if (base >= (unsigned int)TOTAL_) return;
    float4 v; float* pv = &v.x;
#pragma unroll
    for (int u = 0; u < 4; ++u) {
        unsigned int idx = base + u;
        unsigned int bh     = idx / (unsigned int)PLANE_;
        unsigned int within = idx - bh * (unsigned int)PLANE_;
        unsigned int h = bh & (H_ - 1);
        unsigned int i = within / (unsigned int)N1_;
        unsigned int j = within - i * (unsigned int)N1_;
        pv[u] = (i == 0u || j == 0u) ? virtual_w[h] : 0.0f;
    }
    *reinterpret_cast<float4*>(out + base) = v;
}

__global__ __launch_bounds__(256) void edge_kernel(
    const float4* __restrict__ edge_feat, const int* __restrict__ edge_index,
    const void* __restrict__ edge_mask, const int* __restrict__ nlig,
    const float* __restrict__ structural_w, const float* __restrict__ plip_protein_w,
    const float* __restrict__ plip_ligand_w, const float* __restrict__ plip_inter_w,
    const float* __restrict__ loc_w, const float* __restrict__ W1,
    const float* __restrict__ b1, const float* __restrict__ W2,
    const float* __restrict__ b2, float* __restrict__ out)
{
    __shared__ float sW2[H_ * H_];
    __shared__ float sW1[H_], sb1[H_], sb2[H_];
    __shared__ float sStruct[20 * H_];
    __shared__ float sPlipP[15 * H_], sPlipL[15 * H_], sPlipI[15 * H_];
    __shared__ float sLoc[4 * H_];

    for (int i = threadIdx.x; i < H_ * H_; i += blockDim.x) sW2[i] = W2[i];
    if (threadIdx.x < H_) {
        sW1[threadIdx.x] = W1[threadIdx.x];
        sb1[threadIdx.x] = b1[threadIdx.x];
        sb2[threadIdx.x] = b2[threadIdx.x];
    }
    for (int i = threadIdx.x; i < 20 * H_; i += blockDim.x) sStruct[i] = structural_w[i];
    for (int i = threadIdx.x; i < 15 * H_; i += blockDim.x) {
        sPlipP[i] = plip_protein_w[i]; sPlipL[i] = plip_ligand_w[i]; sPlipI[i] = plip_inter_w[i];
    }
    for (int i = threadIdx.x; i < 4 * H_; i += blockDim.x) sLoc[i] = loc_w[i];

    int lane = threadIdx.x & 63;
    int probe = ((const int*)edge_mask)[lane];
    bool byte_mask = __any(probe != 0 && probe != 1);
    __syncthreads();

    int gid = blockIdx.x * blockDim.x + threadIdx.x;
    int b = gid >> 13, e = gid & (E_ - 1);
    bool m = byte_mask ? (((const unsigned char*)edge_mask)[gid] != 0)
                       : (((const int*)edge_mask)[gid] != 0);
    if (!m) return;
    int src = edge_index[(b * 2 + 0) * E_ + e];
    int tgt = edge_index[(b * 2 + 1) * E_ + e];
    if (src < 0 || src >= NN_ || tgt < 0 || tgt >= NN_) return;
    if (src == 0 && tgt == 0) return;

    float4 ef = edge_feat[gid];
    int c0 = (int)ef.x, c1 = (int)ef.y, c2 = (int)ef.z;
    float dist = ef.w;
    const float* type_ptr = nullptr; const float* loc_ptr = nullptr;
    if (c0 == 0 || c0 == 1) {
        int si = min(max(c0 * 4 + c1 * 2 + c2, 0), 19);
        type_ptr = &sStruct[si * H_];
    } else if (c0 == 5) {
        int pi = min(max(c1, 0), 14);
        int nl = nlig[b];
        bool sl = src < nl, tl = tgt < nl;
        const float* pw; int loc;
        if (sl && tl)        { pw = sPlipL; loc = 0; }
        else if (!sl && !tl) { pw = sPlipP; loc = 1; }
        else                 { pw = sPlipI; loc = 2; }
        type_ptr = &pw[pi * H_]; loc_ptr = &sLoc[loc * H_];
    }
    float hk[H_];
#pragma unroll
    for (int k = 0; k < H_; ++k) {
        float v = fmaf(dist, sW1[k], sb1[k]);
        hk[k] = v > 0.0f ? v : 0.0f;
    }
    int s1 = src + 1, t1 = tgt + 1;
    float* outb = out + (size_t)b * H_ * PLANE_;
    int off1 = s1 * N1_ + t1, off2 = t1 * N1_ + s1;
#pragma unroll 4
    for (int h = 0; h < H_; ++h) {
        float acc = sb2[h];
#pragma unroll
        for (int k = 0; k < H_; ++k) acc = fmaf(hk[k], sW2[h * H_ + k], acc);
        if (type_ptr) acc += type_ptr[h];
        if (loc_ptr)  acc += loc_ptr[h];
        float* p = outb + (size_t)h * PLANE_;
        unsafeAtomicAdd(p + off1, acc);
        unsafeAtomicAdd(p + off2, acc);
    }
}

// ============================================================================
extern "C" void kernel_launch(void* const* d_in, const int* in_sizes, int n_in,
                              void* d_out, int out_size, void* d_ws, size_t ws_size,
                              hipStream_t stream)
{
    const float4* edge_feat      = (const float4*)d_in[0];
    const int*    edge_index     = (const int*)  d_in[2];
    const void*   edge_mask      =               d_in[3];
    const int*    nlig           = (const int*)  d_in[4];
    const float*  structural_w   = (const float*)d_in[5];
    const float*  plip_protein_w = (const float*)d_in[6];
    const float*  plip_ligand_w  = (const float*)d_in[7];
    const float*  plip_inter_w   = (const float*)d_in[8];
    const float*  loc_w          = (const float*)d_in[9];
    const float*  virtual_w      = (const float*)d_in[10];
    const float*  W1             = (const float*)d_in[11];
    const float*  b1             = (const float*)d_in[12];
    const float*  W2             = (const float*)d_in[13];
    const float*  b2             = (const float*)d_in[14];
    float* out = (float*)d_out;

    const size_t counts_off = 0;
    const size_t bins_off   = 65536;
    const size_t need = bins_off + (size_t)NBIN_ * CAP_ * sizeof(int);

    if (ws_size >= need) {
        int* counts = (int*)((char*)d_ws + counts_off);
        int* bins   = (int*)((char*)d_ws + bins_off);

        zero_counts_kernel<<<(NBIN_ + 255) / 256, 256, 0, stream>>>(counts);
        bin_kernel<<<(B_ * E_) / 256, 256, 0, stream>>>(edge_index, edge_mask, nlig, counts, bins);
        row_kernel<<<B_ * N1_ * 2, 256, 0, stream>>>(
            edge_feat, structural_w, plip_protein_w, plip_ligand_w, plip_inter_w,
            loc_w, virtual_w, W1, b1, W2, b2, counts, bins, out);
    } else {
        unsigned int nth  = (unsigned int)(TOTAL_ / 4);
        unsigned int nblk = (nth + 255u) / 256u;
        init_out_kernel<<<nblk, 256, 0, stream>>>(out, virtual_w);
        edge_kernel<<<(B_ * E_) / 256, 256, 0, stream>>>(
            edge_feat, edge_index, edge_mask, nlig,
            structural_w, plip_protein_w, plip_ligand_w, plip_inter_w,
            loc_w, W1, b1, W2, b2, out);
    }
}

// Round 4
// 137.866 us; speedup vs baseline: 2.9981x; 1.0113x over previous
//
#include <hip/hip_runtime.h>
#include <hip/hip_bf16.h>

#define B_  16
#define E_  8192
#define NN_ 384
#define N1_ 385
#define H_  32
#define HH_ 16                      // h per block (half)
#define PLANE_ (N1_ * N1_)          // 148225
#define TOTAL_ (B_ * H_ * PLANE_)   // 75,891,200
#define CAP_ 128                    // bin capacity (avg fill ~38, max ~66)
#define NBIN_ (B_ * N1_)            // 6160 bins keyed by (b, row_index_1based)
#define STRIDE_ 396                 // srow row stride: %4==0 (b128), %32==12 (2-way max on atomics)
#define TS_ 20                      // small-table stride: 20r mod 32 spreads groups

// workspace layout (bytes)
#define WS_COUNTS 0                           // 6160 * 4 = 24640
#define WS_T      32768                       // 32 * 4
#define WS_A      33024                       // 33*32*4 = 4224
#define WS_B      (33024 + 33*32*4)           // 4224, ends 41472 < 65536
#define WS_BINS   65536                       // 6160*128*4 = 3,153,920
#define WS_BINSD  (65536 + NBIN_*CAP_*4)
#define WS_NEED   ((size_t)WS_BINSD + (size_t)NBIN_*CAP_*4)   // 6,373,376

// ============================================================================
// FAST PATH
// ============================================================================

__global__ __launch_bounds__(256) void zero_counts_kernel(int* __restrict__ counts)
{
    int i = blockIdx.x * blockDim.x + threadIdx.x;
    if (i < NBIN_) counts[i] = 0;
}

// One block. The dist-MLP  f_h(d) = b2_h + sum_k relu(d*W1_k + b1_k) * W2[h][k]
// is piecewise-linear in d with breakpoints t_k = -b1_k/W1_k. Precompute per
// sorted-segment s in [0,32]:  f_h(d) = A[s][h] + d * Bv[s][h].
__global__ __launch_bounds__(256) void setup_ab_kernel(
    const float* __restrict__ W1, const float* __restrict__ b1,
    const float* __restrict__ W2, const float* __restrict__ b2,
    float* __restrict__ T, float* __restrict__ A, float* __restrict__ Bv)
{
    __shared__ float sTv[32];   // raw breakpoints
    __shared__ float sT[32];    // sorted
    __shared__ float sW1[32], sb1[32];
    int tid = threadIdx.x;
    if (tid < 32) {
        float w = W1[tid], b = b1[tid];
        sW1[tid] = w; sb1[tid] = b;
        sTv[tid] = (w != 0.0f) ? (-b / w) : -3.402823e38f;  // W1==0: constant, sentinel
    }
    __syncthreads();
    if (tid < 32) {                 // rank sort (stable)
        float t = sTv[tid];
        int rank = 0;
        for (int j = 0; j < 32; ++j) {
            float tj = sTv[j];
            rank += (tj < t || (tj == t && j < tid)) ? 1 : 0;
        }
        sT[rank] = t;
    }
    __syncthreads();
    if (tid < 32) T[tid] = sT[tid];
    for (int idx = tid; idx < 33 * 32; idx += 256) {
        int s = idx >> 5, h = idx & 31;
        float m;                    // representative point of segment s
        if (s == 0)       m = sT[0] - 1.0f;
        else if (s == 32) m = sT[31] + 1.0f;
        else              m = 0.5f * (sT[s - 1] + sT[s]);
        float alpha = b2[h], beta = 0.0f;
        for (int k = 0; k < 32; ++k) {
            float w = sW1[k], b = sb1[k];
            bool act = (w > 0.0f) ? (m > -b / w)
                     : (w < 0.0f) ? (m < -b / w) : (b > 0.0f);
            if (act) {
                float w2 = W2[h * 32 + k];
                alpha = fmaf(w2, b, alpha);
                beta  = fmaf(w2, w, beta);
            }
        }
        A[idx] = alpha; Bv[idx] = beta;
    }
}

// Per valid edge: push {type-row r, other-endpoint, dist} into both endpoint bins.
// meta = (r<<9) | other  (r in [0,65], other in [1,384])
__global__ __launch_bounds__(256) void bin_kernel(
    const float4* __restrict__ edge_feat,   // (B,E,4)
    const int*    __restrict__ edge_index,  // (B,2,E)
    const void*   __restrict__ edge_mask,   // (B,E) bool(1B) or int32 — detected
    const int*    __restrict__ nlig,        // (B,)
    int* __restrict__ counts, int* __restrict__ bins, float* __restrict__ binsD)
{
    int lane = threadIdx.x & 63;
    int probe = ((const int*)edge_mask)[lane];
    bool byte_mask = __any(probe != 0 && probe != 1);

    int gid = blockIdx.x * blockDim.x + threadIdx.x;   // exact grid: B*E
    int b = gid >> 13, e = gid & (E_ - 1);
    bool m = byte_mask ? (((const unsigned char*)edge_mask)[gid] != 0)
                       : (((const int*)edge_mask)[gid] != 0);
    if (!m) return;
    int src = edge_index[(b * 2 + 0) * E_ + e];
    int tgt = edge_index[(b * 2 + 1) * E_ + e];
    if (src < 0 || src >= NN_ || tgt < 0 || tgt >= NN_) return;
    if (src == 0 && tgt == 0) return;

    float4 ef = edge_feat[gid];
    int c0 = (int)ef.x, c1 = (int)ef.y, c2 = (int)ef.z;
    float dist = ef.w;

    int r;
    if (c0 == 0 || c0 == 1) {
        r = min(max(c0 * 4 + c1 * 2 + c2, 0), 19);
    } else if (c0 == 5) {
        int pi = min(max(c1, 0), 14);
        int nl = nlig[b];
        bool sl = src < nl, tl = tgt < nl;
        int loc = (sl && tl) ? 0 : ((!sl && !tl) ? 1 : 2);
        r = 20 + loc * 15 + pi;
    } else r = 65;   // zero row

    int s1 = src + 1, t1 = tgt + 1;
    int bin1 = b * N1_ + s1, bin2 = b * N1_ + t1;
    int p = atomicAdd(&counts[bin1], 1);
    if (p < CAP_) { bins[bin1 * CAP_ + p] = (r << 9) | t1; binsD[bin1 * CAP_ + p] = dist; }
    p = atomicAdd(&counts[bin2], 1);
    if (p < CAP_) { bins[bin2 * CAP_ + p] = (r << 9) | s1; binsD[bin2 * CAP_ + p] = dist; }
}

// One workgroup per (b, i, h-half). LDS rows are SHIFTED so both LDS and
// global accesses are 16B-aligned: value for column t lives at 4 + t - off,
// off = (-(h+i)) & 3 = first aligned global column.
__global__ __launch_bounds__(256) void row_kernel(
    const float* __restrict__ structural_w,   // (20,H)
    const float* __restrict__ plip_protein_w, // (15,H)
    const float* __restrict__ plip_ligand_w,  // (15,H)
    const float* __restrict__ plip_inter_w,   // (15,H)
    const float* __restrict__ loc_w,          // (4,H)
    const float* __restrict__ virtual_w,      // (1,H)
    const float* __restrict__ T,              // (32)
    const float* __restrict__ A,              // (33,32)
    const float* __restrict__ Bv,             // (33,32)
    const int*   __restrict__ counts,         // (NBIN_)
    const int*   __restrict__ bins,           // (NBIN_,CAP_)
    const float* __restrict__ binsD,          // (NBIN_,CAP_)
    float* __restrict__ out)                  // (B,H,N1,N1)
{
    __shared__ float4 srow4[HH_ * (STRIDE_ / 4)];   // 16 rows * 396 floats = 25344 B
    __shared__ float sA[33 * TS_], sB[33 * TS_];    // 2640 B each
    __shared__ float sType[66 * TS_];               // 5280 B

    float* srow = reinterpret_cast<float*>(srow4);

    int half  = blockIdx.x & 1;
    int rowid = blockIdx.x >> 1;        // 0 .. B*N1-1
    int b = rowid / N1_;
    int i = rowid - b * N1_;
    int h0 = half << 4;
    int tid = threadIdx.x;
    int wv = tid >> 6, lane = tid & 63;

    // ---- stage tables ----
    for (int idx = tid; idx < 33 * 16; idx += 256) {
        int s = idx >> 4, hh = idx & 15;
        sA[s * TS_ + hh] = A[s * 32 + h0 + hh];
        sB[s * TS_ + hh] = Bv[s * 32 + h0 + hh];
    }
    for (int idx = tid; idx < 66 * 16; idx += 256) {
        int r = idx >> 4, hh = idx & 15;
        float v;
        if (r < 20) v = structural_w[r * 32 + h0 + hh];
        else if (r < 65) {
            int t2 = r - 20;
            int loc = t2 / 15, pi = t2 - loc * 15;
            const float* pw = (loc == 0) ? plip_ligand_w
                            : (loc == 1) ? plip_protein_w : plip_inter_w;
            v = pw[pi * 32 + h0 + hh] + loc_w[loc * 32 + h0 + hh];
        } else v = 0.0f;
        sType[r * TS_ + hh] = v;
    }

    // breakpoints -> registers (loop-invariant; static indexing only)
    float tr[32];
#pragma unroll
    for (int q = 0; q < 8; ++q) {
        float4 tv = *reinterpret_cast<const float4*>(T + 4 * q);
        tr[4 * q] = tv.x; tr[4 * q + 1] = tv.y; tr[4 * q + 2] = tv.z; tr[4 * q + 3] = tv.w;
    }

    // ---- init rows (vector fill; wave wv owns rows wv, wv+4, ...) ----
    for (int hh = wv; hh < HH_; hh += 4) {
        float vw = virtual_w[h0 + hh];
        float fill = (i == 0) ? vw : 0.0f;
        float4 f4 = make_float4(fill, fill, fill, fill);
        float4* rp = &srow4[hh * (STRIDE_ / 4)];
        for (int c = lane; c < STRIDE_ / 4; c += 64) rp[c] = f4;
    }
    __syncthreads();

    // virtual column t=0 (disjoint from all scatter targets, other >= 1)
    if (tid < HH_ && i != 0) {
        int hh = tid;
        int off = (4 - ((h0 + hh + i) & 3)) & 3;
        srow[hh * STRIDE_ + 4 - off] = virtual_w[h0 + hh];
    }

    // ---- gather: 16 groups of 16 lanes; lane-in-group = hh ----
    int cnt = counts[rowid]; cnt = cnt < CAP_ ? cnt : CAP_;
    int grp = tid >> 4, hh = tid & 15;
    int off_hh = (4 - ((h0 + hh + i) & 3)) & 3;
    int rowbase = hh * STRIDE_ + 4 - off_hh;
    for (int j = grp; j < cnt; j += 16) {
        int   meta = bins[rowid * CAP_ + j];
        float dist = binsD[rowid * CAP_ + j];
        int other = meta & 0x1FF;
        int r = meta >> 9;
        // segment = #{breakpoints < dist}: 32 independent register compares
        int lo = 0;
#pragma unroll
        for (int k = 0; k < 32; ++k) lo += (tr[k] < dist) ? 1 : 0;
        float acc = fmaf(dist, sB[lo * TS_ + hh], sA[lo * TS_ + hh]) + sType[r * TS_ + hh];
        atomicAdd(&srow[rowbase + other], acc);
    }
    __syncthreads();

    // ---- writeout: aligned b128 LDS reads -> aligned dwordx4 stores ----
    for (int hh2 = wv; hh2 < HH_; hh2 += 4) {
        int h = h0 + hh2;
        const float* rr = &srow[hh2 * STRIDE_];
        float* dst = out + ((size_t)(b * H_ + h)) * PLANE_ + (size_t)i * N1_;
        int off = (4 - ((h + i) & 3)) & 3;
        if (lane < off) dst[lane] = rr[4 - off + lane];
        int nvec = (N1_ - off) >> 2;                  // 95 or 96
        for (int q = lane; q < nvec; q += 64) {
            float4 v = *reinterpret_cast<const float4*>(rr + 4 + 4 * q);
            *reinterpret_cast<float4*>(dst + off + 4 * q) = v;
        }
        int done = off + (nvec << 2);
        int rem = N1_ - done;                         // 0..3
        if (lane < rem) dst[done + lane] = rr[4 + 4 * nvec + lane];
    }
}

// ============================================================================
// FALLBACK PATH (round-1, passing): used only if ws_size is too small.
// ============================================================================

__global__ __launch_bounds__(256) void init_out_kernel(
    float* __restrict__ out, const float* __restrict__ virtual_w)
{
    unsigned int tid = blockIdx.x * blockDim.x + threadIdx.x;
    unsigned int base = tid * 4u;
    if (base >= (unsigned int)TOTAL_) return;
    float4 v; float* pv = &v.x;
#pragma unroll
    for (int u = 0; u < 4; ++u) {
        unsigned int idx = base + u;
        unsigned int bh     = idx / (unsigned int)PLANE_;
        unsigned int within = idx - bh * (unsigned int)PLANE_;
        unsigned int h = bh & (H_ - 1);
        unsigned int i = within / (unsigned int)N1_;
        unsigned int j = within - i * (unsigned int)N1_;
        pv[u] = (i == 0u || j == 0u) ? virtual_w[h] : 0.0f;
    }
    *reinterpret_cast<float4*>(out + base) = v;
}

__global__ __launch_bounds__(256) void edge_kernel(
    const float4* __restrict__ edge_feat, const int* __restrict__ edge_index,
    const void* __restrict__ edge_mask, const int* __restrict__ nlig,
    const float* __restrict__ structural_w, const float* __restrict__ plip_protein_w,
    const float* __restrict__ plip_ligand_w, const float* __restrict__ plip_inter_w,
    const float* __restrict__ loc_w, const float* __restrict__ W1,
    const float* __restrict__ b1, const float* __restrict__ W2,
    const float* __restrict__ b2, float* __restrict__ out)
{
    __shared__ float sW2[H_ * H_];
    __shared__ float sW1[H_], sb1[H_], sb2[H_];
    __shared__ float sStruct[20 * H_];
    __shared__ float sPlipP[15 * H_], sPlipL[15 * H_], sPlipI[15 * H_];
    __shared__ float sLoc[4 * H_];

    for (int i = threadIdx.x; i < H_ * H_; i += blockDim.x) sW2[i] = W2[i];
    if (threadIdx.x < H_) {
        sW1[threadIdx.x] = W1[threadIdx.x];
        sb1[threadIdx.x] = b1[threadIdx.x];
        sb2[threadIdx.x] = b2[threadIdx.x];
    }
    for (int i = threadIdx.x; i < 20 * H_; i += blockDim.x) sStruct[i] = structural_w[i];
    for (int i = threadIdx.x; i < 15 * H_; i += blockDim.x) {
        sPlipP[i] = plip_protein_w[i]; sPlipL[i] = plip_ligand_w[i]; sPlipI[i] = plip_inter_w[i];
    }
    for (int i = threadIdx.x; i < 4 * H_; i += blockDim.x) sLoc[i] = loc_w[i];

    int lane = threadIdx.x & 63;
    int probe = ((const int*)edge_mask)[lane];
    bool byte_mask = __any(probe != 0 && probe != 1);
    __syncthreads();

    int gid = blockIdx.x * blockDim.x + threadIdx.x;
    int b = gid >> 13, e = gid & (E_ - 1);
    bool m = byte_mask ? (((const unsigned char*)edge_mask)[gid] != 0)
                       : (((const int*)edge_mask)[gid] != 0);
    if (!m) return;
    int src = edge_index[(b * 2 + 0) * E_ + e];
    int tgt = edge_index[(b * 2 + 1) * E_ + e];
    if (src < 0 || src >= NN_ || tgt < 0 || tgt >= NN_) return;
    if (src == 0 && tgt == 0) return;

    float4 ef = edge_feat[gid];
    int c0 = (int)ef.x, c1 = (int)ef.y, c2 = (int)ef.z;
    float dist = ef.w;
    const float* type_ptr = nullptr; const float* loc_ptr = nullptr;
    if (c0 == 0 || c0 == 1) {
        int si = min(max(c0 * 4 + c1 * 2 + c2, 0), 19);
        type_ptr = &sStruct[si * H_];
    } else if (c0 == 5) {
        int pi = min(max(c1, 0), 14);
        int nl = nlig[b];
        bool sl = src < nl, tl = tgt < nl;
        const float* pw; int loc;
        if (sl && tl)        { pw = sPlipL; loc = 0; }
        else if (!sl && !tl) { pw = sPlipP; loc = 1; }
        else                 { pw = sPlipI; loc = 2; }
        type_ptr = &pw[pi * H_]; loc_ptr = &sLoc[loc * H_];
    }
    float hk[H_];
#pragma unroll
    for (int k = 0; k < H_; ++k) {
        float v = fmaf(dist, sW1[k], sb1[k]);
        hk[k] = v > 0.0f ? v : 0.0f;
    }
    int s1 = src + 1, t1 = tgt + 1;
    float* outb = out + (size_t)b * H_ * PLANE_;
    int off1 = s1 * N1_ + t1, off2 = t1 * N1_ + s1;
#pragma unroll 4
    for (int h = 0; h < H_; ++h) {
        float acc = sb2[h];
#pragma unroll
        for (int k = 0; k < H_; ++k) acc = fmaf(hk[k], sW2[h * H_ + k], acc);
        if (type_ptr) acc += type_ptr[h];
        if (loc_ptr)  acc += loc_ptr[h];
        float* p = outb + (size_t)h * PLANE_;
        unsafeAtomicAdd(p + off1, acc);
        unsafeAtomicAdd(p + off2, acc);
    }
}

// ============================================================================
extern "C" void kernel_launch(void* const* d_in, const int* in_sizes, int n_in,
                              void* d_out, int out_size, void* d_ws, size_t ws_size,
                              hipStream_t stream)
{
    const float4* edge_feat      = (const float4*)d_in[0];
    const int*    edge_index     = (const int*)  d_in[2];
    const void*   edge_mask      =               d_in[3];
    const int*    nlig           = (const int*)  d_in[4];
    const float*  structural_w   = (const float*)d_in[5];
    const float*  plip_protein_w = (const float*)d_in[6];
    const float*  plip_ligand_w  = (const float*)d_in[7];
    const float*  plip_inter_w   = (const float*)d_in[8];
    const float*  loc_w          = (const float*)d_in[9];
    const float*  virtual_w      = (const float*)d_in[10];
    const float*  W1             = (const float*)d_in[11];
    const float*  b1             = (const float*)d_in[12];
    const float*  W2             = (const float*)d_in[13];
    const float*  b2             = (const float*)d_in[14];
    float* out = (float*)d_out;

    if (ws_size >= WS_NEED) {
        char* ws = (char*)d_ws;
        int*   counts = (int*)  (ws + WS_COUNTS);
        float* T      = (float*)(ws + WS_T);
        float* A      = (float*)(ws + WS_A);
        float* Bv     = (float*)(ws + WS_B);
        int*   bins   = (int*)  (ws + WS_BINS);
        float* binsD  = (float*)(ws + WS_BINSD);

        zero_counts_kernel<<<(NBIN_ + 255) / 256, 256, 0, stream>>>(counts);
        setup_ab_kernel<<<1, 256, 0, stream>>>(W1, b1, W2, b2, T, A, Bv);
        bin_kernel<<<(B_ * E_) / 256, 256, 0, stream>>>(
            edge_feat, edge_index, edge_mask, nlig, counts, bins, binsD);
        row_kernel<<<B_ * N1_ * 2, 256, 0, stream>>>(
            structural_w, plip_protein_w, plip_ligand_w, plip_inter_w,
            loc_w, virtual_w, T, A, Bv, counts, bins, binsD, out);
    } else {
        unsigned int nth  = (unsigned int)(TOTAL_ / 4);
        unsigned int nblk = (nth + 255u) / 256u;
        init_out_kernel<<<nblk, 256, 0, stream>>>(out, virtual_w);
        edge_kernel<<<(B_ * E_) / 256, 256, 0, stream>>>(
            edge_feat, edge_index, edge_mask, nlig,
            structural_w, plip_protein_w, plip_ligand_w, plip_inter_w,
            loc_w, W1, b1, W2, b2, out);
    }
}

// Round 5
// 117.480 us; speedup vs baseline: 3.5183x; 1.1735x over previous
//
#include <hip/hip_runtime.h>
#include <hip/hip_bf16.h>

#define B_  16
#define E_  8192
#define NN_ 384
#define N1_ 385
#define H_  32
#define HH_ 16                      // h per block (half)
#define PLANE_ (N1_ * N1_)          // 148225
#define TOTAL_ (B_ * H_ * PLANE_)   // 75,891,200
#define CAP_ 128                    // bin capacity (avg fill ~38)
#define NBIN_ (B_ * N1_)            // 6160 bins keyed by (b, row_index_1based)
#define STRIDE_ 396                 // LDS row stride: %4==0 (b128-able), odd-ish banks
#define TS_ 20                      // small-table stride
#define CHUNK_ 5                    // rows per block; 385 = 77*5 exactly
#define NCH_ 77

// workspace layout (bytes)
#define WS_COUNTS 0                           // 6160*4 = 24640
#define WS_T      32768                       // 32*4
#define WS_A      33024                       // 33*32*4 = 4224
#define WS_B      (33024 + 33*32*4)           // ends 41472 < 65536
#define WS_BINS2  65536                       // 6160*128*8 = 6,307,840
#define WS_NEED   ((size_t)WS_BINS2 + (size_t)NBIN_*CAP_*8)   // 6,373,376

// ============================================================================
// FAST PATH
// ============================================================================

// Fused: zero counts (all blocks) + piecewise-linear MLP precompute (block 0).
// f_h(d) = b2_h + sum_k relu(d*W1_k+b1_k)*W2[h][k] is piecewise-linear with
// breakpoints t_k = -b1_k/W1_k; per sorted segment s: f_h(d) = A[s][h]+d*Bv[s][h].
__global__ __launch_bounds__(256) void prep_kernel(
    const float* __restrict__ W1, const float* __restrict__ b1,
    const float* __restrict__ W2, const float* __restrict__ b2,
    float* __restrict__ T, float* __restrict__ A, float* __restrict__ Bv,
    int* __restrict__ counts)
{
    int g = blockIdx.x * 256 + threadIdx.x;
    if (g < NBIN_) counts[g] = 0;

    if (blockIdx.x == 0) {
        __shared__ float sTv[32], sT[32], sW1[32], sb1[32];
        int tid = threadIdx.x;
        if (tid < 32) {
            float w = W1[tid], b = b1[tid];
            sW1[tid] = w; sb1[tid] = b;
            sTv[tid] = (w != 0.0f) ? (-b / w) : -3.402823e38f;
        }
        __syncthreads();
        if (tid < 32) {                 // stable rank sort
            float t = sTv[tid];
            int rank = 0;
            for (int j = 0; j < 32; ++j) {
                float tj = sTv[j];
                rank += (tj < t || (tj == t && j < tid)) ? 1 : 0;
            }
            sT[rank] = t;
        }
        __syncthreads();
        if (tid < 32) T[tid] = sT[tid];
        for (int idx = tid; idx < 33 * 32; idx += 256) {
            int s = idx >> 5, h = idx & 31;
            float m;
            if (s == 0)       m = sT[0] - 1.0f;
            else if (s == 32) m = sT[31] + 1.0f;
            else              m = 0.5f * (sT[s - 1] + sT[s]);
            float alpha = b2[h], beta = 0.0f;
            for (int k = 0; k < 32; ++k) {
                float w = sW1[k], b = sb1[k];
                bool act = (w > 0.0f) ? (m > -b / w)
                         : (w < 0.0f) ? (m < -b / w) : (b > 0.0f);
                if (act) {
                    float w2 = W2[h * 32 + k];
                    alpha = fmaf(w2, b, alpha);
                    beta  = fmaf(w2, w, beta);
                }
            }
            A[idx] = alpha; Bv[idx] = beta;
        }
    }
}

// Per valid edge: push {type-row r, other-endpoint, dist} into both endpoint bins.
// meta = (r<<9) | other  (r in [0,65], other in [1,384])
__global__ __launch_bounds__(256) void bin_kernel(
    const float4* __restrict__ edge_feat,   // (B,E,4)
    const int*    __restrict__ edge_index,  // (B,2,E)
    const void*   __restrict__ edge_mask,   // (B,E) bool(1B) or int32 — detected
    const int*    __restrict__ nlig,        // (B,)
    int* __restrict__ counts, int2* __restrict__ bins2)
{
    int lane = threadIdx.x & 63;
    int probe = ((const int*)edge_mask)[lane];
    bool byte_mask = __any(probe != 0 && probe != 1);

    int gid = blockIdx.x * blockDim.x + threadIdx.x;   // exact grid: B*E
    int b = gid >> 13, e = gid & (E_ - 1);
    bool m = byte_mask ? (((const unsigned char*)edge_mask)[gid] != 0)
                       : (((const int*)edge_mask)[gid] != 0);
    if (!m) return;
    int src = edge_index[(b * 2 + 0) * E_ + e];
    int tgt = edge_index[(b * 2 + 1) * E_ + e];
    if (src < 0 || src >= NN_ || tgt < 0 || tgt >= NN_) return;
    if (src == 0 && tgt == 0) return;

    float4 ef = edge_feat[gid];
    int c0 = (int)ef.x, c1 = (int)ef.y, c2 = (int)ef.z;
    float dist = ef.w;

    int r;
    if (c0 == 0 || c0 == 1) {
        r = min(max(c0 * 4 + c1 * 2 + c2, 0), 19);
    } else if (c0 == 5) {
        int pi = min(max(c1, 0), 14);
        int nl = nlig[b];
        bool sl = src < nl, tl = tgt < nl;
        int loc = (sl && tl) ? 0 : ((!sl && !tl) ? 1 : 2);
        r = 20 + loc * 15 + pi;
    } else r = 65;   // zero row

    int s1 = src + 1, t1 = tgt + 1;
    int db = __float_as_int(dist);
    int bin1 = b * N1_ + s1, bin2 = b * N1_ + t1;
    int p = atomicAdd(&counts[bin1], 1);
    if (p < CAP_) bins2[bin1 * CAP_ + p] = make_int2((r << 9) | t1, db);
    p = atomicAdd(&counts[bin2], 1);
    if (p < CAP_) bins2[bin2 * CAP_ + p] = make_int2((r << 9) | s1, db);
}

// One block per (b, half, 5-row chunk). Each WAVE owns 4 h-planes (its own
// LDS strip) and pipelines rows with NO intra-loop barriers (LDS is in-order
// per wave; strips are wave-private; tables are read-only after one barrier).
// LDS rows are SHIFTED: value for column t lives at (4-off)+t, off=(-(h+i))&3,
// so both ds_*_b128 and global dwordx4 are 16B-aligned.
__global__ __launch_bounds__(256, 4) void chunk_kernel(
    const float* __restrict__ structural_w,   // (20,H)
    const float* __restrict__ plip_protein_w, // (15,H)
    const float* __restrict__ plip_ligand_w,  // (15,H)
    const float* __restrict__ plip_inter_w,   // (15,H)
    const float* __restrict__ loc_w,          // (4,H)
    const float* __restrict__ virtual_w,      // (1,H)
    const float* __restrict__ T,              // (32)
    const float* __restrict__ A,              // (33,32)
    const float* __restrict__ Bv,             // (33,32)
    const int*   __restrict__ counts,         // (NBIN_)
    const int2*  __restrict__ bins2,          // (NBIN_,CAP_)
    float* __restrict__ out)                  // (B,H,N1,N1)
{
    __shared__ float srow[HH_ * STRIDE_];           // 25344 B; wave w owns rows 4w..4w+3
    __shared__ float sA[33 * TS_], sB[33 * TS_];    // 2640 B each
    __shared__ float sType[66 * TS_];               // 5280 B

    int bid = blockIdx.x;
    int chunk = bid % NCH_;
    int rest  = bid / NCH_;          // 0..31
    int half = rest & 1;
    int b = rest >> 1;
    int h0 = half << 4;
    int tid = threadIdx.x;
    int wv = tid >> 6, lane = tid & 63;

    // ---- stage tables (once per block) ----
    for (int idx = tid; idx < 33 * 16; idx += 256) {
        int s = idx >> 4, hh = idx & 15;
        sA[s * TS_ + hh] = A[s * 32 + h0 + hh];
        sB[s * TS_ + hh] = Bv[s * 32 + h0 + hh];
    }
    for (int idx = tid; idx < 66 * 16; idx += 256) {
        int r = idx >> 4, hh = idx & 15;
        float v;
        if (r < 20) v = structural_w[r * 32 + h0 + hh];
        else if (r < 65) {
            int t2 = r - 20;
            int loc = t2 / 15, pi = t2 - loc * 15;
            const float* pw = (loc == 0) ? plip_ligand_w
                            : (loc == 1) ? plip_protein_w : plip_inter_w;
            v = pw[pi * 32 + h0 + hh] + loc_w[loc * 32 + h0 + hh];
        } else v = 0.0f;
        sType[r * TS_ + hh] = v;
    }

    // breakpoints -> registers (static indexing only)
    float tr[32];
#pragma unroll
    for (int q = 0; q < 8; ++q) {
        float4 tv = *reinterpret_cast<const float4*>(T + 4 * q);
        tr[4 * q] = tv.x; tr[4 * q + 1] = tv.y; tr[4 * q + 2] = tv.z; tr[4 * q + 3] = tv.w;
    }
    __syncthreads();                 // the ONLY block barrier

    int hh_q = lane & 3;             // hh within wave's quad
    int slot = lane >> 2;            // entry slot 0..15
    int hhg  = (wv << 2) | hh_q;     // hh within half, 0..15
    int hq   = h0 + hhg;             // global h for gather lane
    float* sW = srow + (wv << 2) * STRIDE_;   // wave-private strip (4 rows)

    // wave-invariant per-lane virtual values for the 4 owned h rows
    int rw = lane >> 4;              // writeout: row 0..3 per 16-lane group
    int sl = lane & 15;
    int hw = h0 + (wv << 2) + rw;

    int i0 = chunk * CHUNK_;
#pragma unroll 1
    for (int ii = 0; ii < CHUNK_; ++ii) {
        int i = i0 + ii;
        int rowid = b * N1_ + i;

        // ---- init wave strip ----
#pragma unroll
        for (int r = 0; r < 4; ++r) {
            float vw = virtual_w[h0 + (wv << 2) + r];
            float fill = (i == 0) ? vw : 0.0f;
            float4 f4 = make_float4(fill, fill, fill, fill);
            float4* rp = reinterpret_cast<float4*>(sW + r * STRIDE_);
            for (int c = lane; c < STRIDE_ / 4; c += 64) rp[c] = f4;
        }
        if (i != 0 && lane < 4) {    // virtual column t=0 (disjoint from scatter)
            int hr = h0 + (wv << 2) + lane;
            int off = (4 - ((hr + i) & 3)) & 3;
            sW[lane * STRIDE_ + 4 - off] = virtual_w[hr];
        }

        // ---- gather (wave-private; no barrier) ----
        int cnt = counts[rowid]; cnt = cnt < CAP_ ? cnt : CAP_;
        int offq = (4 - ((hq + i) & 3)) & 3;
        int base = hh_q * STRIDE_ + 4 - offq;
        for (int j = slot; j < cnt; j += 16) {
            int2 e2 = bins2[rowid * CAP_ + j];
            float dist = __int_as_float(e2.y);
            int other = e2.x & 0x1FF;
            int r = e2.x >> 9;
            int lo = 0;
#pragma unroll
            for (int k = 0; k < 32; ++k) lo += (tr[k] < dist) ? 1 : 0;
            float acc = fmaf(dist, sB[lo * TS_ + hhg], sA[lo * TS_ + hhg])
                      + sType[r * TS_ + hhg];
            atomicAdd(&sW[base + other], acc);
        }

        // ---- writeout (wave-private; LDS in-order guarantees atomics done) ----
        {
            const float* rr = sW + rw * STRIDE_;
            float* dst = out + ((size_t)(b * H_ + hw)) * PLANE_ + (size_t)i * N1_;
            int off = (4 - ((hw + i) & 3)) & 3;
            if (sl < off) dst[sl] = rr[4 - off + sl];
            int nvec = (N1_ - off) >> 2;            // 95 or 96
            for (int q = sl; q < nvec; q += 16) {   // 6 iterations
                float4 v = *reinterpret_cast<const float4*>(rr + 4 + 4 * q);
                *reinterpret_cast<float4*>(dst + off + 4 * q) = v;
            }
            int done = off + (nvec << 2);
            int rem = N1_ - done;                   // 0..3
            if (sl < rem) dst[done + sl] = rr[4 + 4 * nvec + sl];
        }
    }
}

// ============================================================================
// FALLBACK PATH (round-1, passing): used only if ws_size is too small.
// ============================================================================

__global__ __launch_bounds__(256) void init_out_kernel(
    float* __restrict__ out, const float* __restrict__ virtual_w)
{
    unsigned int tid = blockIdx.x * blockDim.x + threadIdx.x;
    unsigned int base = tid * 4u;
    if (base >= (unsigned int)TOTAL_) return;
    float4 v; float* pv = &v.x;
#pragma unroll
    for (int u = 0; u < 4; ++u) {
        unsigned int idx = base + u;
        unsigned int bh     = idx / (unsigned int)PLANE_;
        unsigned int within = idx - bh * (unsigned int)PLANE_;
        unsigned int h = bh & (H_ - 1);
        unsigned int i = within / (unsigned int)N1_;
        unsigned int j = within - i * (unsigned int)N1_;
        pv[u] = (i == 0u || j == 0u) ? virtual_w[h] : 0.0f;
    }
    *reinterpret_cast<float4*>(out + base) = v;
}

__global__ __launch_bounds__(256) void edge_kernel(
    const float4* __restrict__ edge_feat, const int* __restrict__ edge_index,
    const void* __restrict__ edge_mask, const int* __restrict__ nlig,
    const float* __restrict__ structural_w, const float* __restrict__ plip_protein_w,
    const float* __restrict__ plip_ligand_w, const float* __restrict__ plip_inter_w,
    const float* __restrict__ loc_w, const float* __restrict__ W1,
    const float* __restrict__ b1, const float* __restrict__ W2,
    const float* __restrict__ b2, float* __restrict__ out)
{
    __shared__ float sW2[H_ * H_];
    __shared__ float sW1[H_], sb1[H_], sb2[H_];
    __shared__ float sStruct[20 * H_];
    __shared__ float sPlipP[15 * H_], sPlipL[15 * H_], sPlipI[15 * H_];
    __shared__ float sLoc[4 * H_];

    for (int i = threadIdx.x; i < H_ * H_; i += blockDim.x) sW2[i] = W2[i];
    if (threadIdx.x < H_) {
        sW1[threadIdx.x] = W1[threadIdx.x];
        sb1[threadIdx.x] = b1[threadIdx.x];
        sb2[threadIdx.x] = b2[threadIdx.x];
    }
    for (int i = threadIdx.x; i < 20 * H_; i += blockDim.x) sStruct[i] = structural_w[i];
    for (int i = threadIdx.x; i < 15 * H_; i += blockDim.x) {
        sPlipP[i] = plip_protein_w[i]; sPlipL[i] = plip_ligand_w[i]; sPlipI[i] = plip_inter_w[i];
    }
    for (int i = threadIdx.x; i < 4 * H_; i += blockDim.x) sLoc[i] = loc_w[i];

    int lane = threadIdx.x & 63;
    int probe = ((const int*)edge_mask)[lane];
    bool byte_mask = __any(probe != 0 && probe != 1);
    __syncthreads();

    int gid = blockIdx.x * blockDim.x + threadIdx.x;
    int b = gid >> 13, e = gid & (E_ - 1);
    bool m = byte_mask ? (((const unsigned char*)edge_mask)[gid] != 0)
                       : (((const int*)edge_mask)[gid] != 0);
    if (!m) return;
    int src = edge_index[(b * 2 + 0) * E_ + e];
    int tgt = edge_index[(b * 2 + 1) * E_ + e];
    if (src < 0 || src >= NN_ || tgt < 0 || tgt >= NN_) return;
    if (src == 0 && tgt == 0) return;

    float4 ef = edge_feat[gid];
    int c0 = (int)ef.x, c1 = (int)ef.y, c2 = (int)ef.z;
    float dist = ef.w;
    const float* type_ptr = nullptr; const float* loc_ptr = nullptr;
    if (c0 == 0 || c0 == 1) {
        int si = min(max(c0 * 4 + c1 * 2 + c2, 0), 19);
        type_ptr = &sStruct[si * H_];
    } else if (c0 == 5) {
        int pi = min(max(c1, 0), 14);
        int nl = nlig[b];
        bool sl = src < nl, tl = tgt < nl;
        const float* pw; int loc;
        if (sl && tl)        { pw = sPlipL; loc = 0; }
        else if (!sl && !tl) { pw = sPlipP; loc = 1; }
        else                 { pw = sPlipI; loc = 2; }
        type_ptr = &pw[pi * H_]; loc_ptr = &sLoc[loc * H_];
    }
    float hk[H_];
#pragma unroll
    for (int k = 0; k < H_; ++k) {
        float v = fmaf(dist, sW1[k], sb1[k]);
        hk[k] = v > 0.0f ? v : 0.0f;
    }
    int s1 = src + 1, t1 = tgt + 1;
    float* outb = out + (size_t)b * H_ * PLANE_;
    int off1 = s1 * N1_ + t1, off2 = t1 * N1_ + s1;
#pragma unroll 4
    for (int h = 0; h < H_; ++h) {
        float acc = sb2[h];
#pragma unroll
        for (int k = 0; k < H_; ++k) acc = fmaf(hk[k], sW2[h * H_ + k], acc);
        if (type_ptr) acc += type_ptr[h];
        if (loc_ptr)  acc += loc_ptr[h];
        float* p = outb + (size_t)h * PLANE_;
        unsafeAtomicAdd(p + off1, acc);
        unsafeAtomicAdd(p + off2, acc);
    }
}

// ============================================================================
extern "C" void kernel_launch(void* const* d_in, const int* in_sizes, int n_in,
                              void* d_out, int out_size, void* d_ws, size_t ws_size,
                              hipStream_t stream)
{
    const float4* edge_feat      = (const float4*)d_in[0];
    const int*    edge_index     = (const int*)  d_in[2];
    const void*   edge_mask      =               d_in[3];
    const int*    nlig           = (const int*)  d_in[4];
    const float*  structural_w   = (const float*)d_in[5];
    const float*  plip_protein_w = (const float*)d_in[6];
    const float*  plip_ligand_w  = (const float*)d_in[7];
    const float*  plip_inter_w   = (const float*)d_in[8];
    const float*  loc_w          = (const float*)d_in[9];
    const float*  virtual_w      = (const float*)d_in[10];
    const float*  W1             = (const float*)d_in[11];
    const float*  b1             = (const float*)d_in[12];
    const float*  W2             = (const float*)d_in[13];
    const float*  b2             = (const float*)d_in[14];
    float* out = (float*)d_out;

    if (ws_size >= WS_NEED) {
        char* ws = (char*)d_ws;
        int*   counts = (int*)  (ws + WS_COUNTS);
        float* T      = (float*)(ws + WS_T);
        float* A      = (float*)(ws + WS_A);
        float* Bv     = (float*)(ws + WS_B);
        int2*  bins2  = (int2*) (ws + WS_BINS2);

        prep_kernel<<<25, 256, 0, stream>>>(W1, b1, W2, b2, T, A, Bv, counts);
        bin_kernel<<<(B_ * E_) / 256, 256, 0, stream>>>(
            edge_feat, edge_index, edge_mask, nlig, counts, bins2);
        chunk_kernel<<<B_ * 2 * NCH_, 256, 0, stream>>>(
            structural_w, plip_protein_w, plip_ligand_w, plip_inter_w,
            loc_w, virtual_w, T, A, Bv, counts, bins2, out);
    } else {
        unsigned int nth  = (unsigned int)(TOTAL_ / 4);
        unsigned int nblk = (nth + 255u) / 256u;
        init_out_kernel<<<nblk, 256, 0, stream>>>(out, virtual_w);
        edge_kernel<<<(B_ * E_) / 256, 256, 0, stream>>>(
            edge_feat, edge_index, edge_mask, nlig,
            structural_w, plip_protein_w, plip_ligand_w, plip_inter_w,
            loc_w, W1, b1, W2, b2, out);
    }
}

// Round 6
// 96.144 us; speedup vs baseline: 4.2991x; 1.2219x over previous
//
#include <hip/hip_runtime.h>
#include <hip/hip_bf16.h>

#define B_  16
#define E_  8192
#define NN_ 384
#define N1_ 385
#define H_  32
#define HH_ 16                      // h-planes per block (half of H)
#define PLANE_ (N1_ * N1_)          // 148225
#define TOTAL_ (B_ * H_ * PLANE_)   // 75,891,200
#define CAP_ 128                    // bin capacity (avg fill ~38)
#define NBIN_ (B_ * N1_)            // 6160 bins keyed by (b, row_index_1based)
#define STRIDE_ 396                 // LDS row stride: %4==0 (float4-able)
#define TS_ 21                      // table stride: gcd(21,32)=1 -> full bank spread
#define CHUNK_ 5                    // rows per block; 385 = 77*5 exactly
#define NCH_ 77

// workspace layout (bytes)
#define WS_COUNTS 0                           // 6160*4 = 24640
#define WS_T      32768                       // 32*4
#define WS_A      33024                       // 33*32*4 = 4224
#define WS_B      (33024 + 33*32*4)           // ends 41472 < 65536
#define WS_BINS2  65536                       // 6160*128*8 = 6,307,840
#define WS_NEED   ((size_t)WS_BINS2 + (size_t)NBIN_*CAP_*8)   // 6,373,376

// ============================================================================
// FAST PATH
// ============================================================================

// Fused: zero counts (all blocks) + piecewise-linear MLP precompute (block 0).
// f_h(d) = b2_h + sum_k relu(d*W1_k+b1_k)*W2[h][k] is piecewise-linear with
// breakpoints t_k = -b1_k/W1_k; per sorted segment s: f_h(d) = A[s][h]+d*Bv[s][h].
__global__ __launch_bounds__(256) void prep_kernel(
    const float* __restrict__ W1, const float* __restrict__ b1,
    const float* __restrict__ W2, const float* __restrict__ b2,
    float* __restrict__ T, float* __restrict__ A, float* __restrict__ Bv,
    int* __restrict__ counts)
{
    int g = blockIdx.x * 256 + threadIdx.x;
    if (g < NBIN_) counts[g] = 0;

    if (blockIdx.x == 0) {
        __shared__ float sTv[32], sT[32], sW1[32], sb1[32];
        int tid = threadIdx.x;
        if (tid < 32) {
            float w = W1[tid], b = b1[tid];
            sW1[tid] = w; sb1[tid] = b;
            sTv[tid] = (w != 0.0f) ? (-b / w) : -3.402823e38f;
        }
        __syncthreads();
        if (tid < 32) {                 // stable rank sort
            float t = sTv[tid];
            int rank = 0;
            for (int j = 0; j < 32; ++j) {
                float tj = sTv[j];
                rank += (tj < t || (tj == t && j < tid)) ? 1 : 0;
            }
            sT[rank] = t;
        }
        __syncthreads();
        if (tid < 32) T[tid] = sT[tid];
        for (int idx = tid; idx < 33 * 32; idx += 256) {
            int s = idx >> 5, h = idx & 31;
            float m;
            if (s == 0)       m = sT[0] - 1.0f;
            else if (s == 32) m = sT[31] + 1.0f;
            else              m = 0.5f * (sT[s - 1] + sT[s]);
            float alpha = b2[h], beta = 0.0f;
            for (int k = 0; k < 32; ++k) {
                float w = sW1[k], b = sb1[k];
                bool act = (w > 0.0f) ? (m > -b / w)
                         : (w < 0.0f) ? (m < -b / w) : (b > 0.0f);
                if (act) {
                    float w2 = W2[h * 32 + k];
                    alpha = fmaf(w2, b, alpha);
                    beta  = fmaf(w2, w, beta);
                }
            }
            A[idx] = alpha; Bv[idx] = beta;
        }
    }
}

// Per valid edge: push entry into both endpoint bins.
// meta = (lo<<16) | (r<<9) | other;  lo = dist's PL segment, r = type row,
// other = opposite endpoint (1-based). dist stored alongside.
__global__ __launch_bounds__(256) void bin_kernel(
    const float4* __restrict__ edge_feat,   // (B,E,4)
    const int*    __restrict__ edge_index,  // (B,2,E)
    const void*   __restrict__ edge_mask,   // (B,E) bool(1B) or int32 — detected
    const int*    __restrict__ nlig,        // (B,)
    const float*  __restrict__ T,           // (32) sorted breakpoints
    int* __restrict__ counts, int2* __restrict__ bins2)
{
    int lane = threadIdx.x & 63;
    int probe = ((const int*)edge_mask)[lane];
    bool byte_mask = __any(probe != 0 && probe != 1);

    int gid = blockIdx.x * blockDim.x + threadIdx.x;   // exact grid: B*E
    int b = gid >> 13, e = gid & (E_ - 1);
    bool m = byte_mask ? (((const unsigned char*)edge_mask)[gid] != 0)
                       : (((const int*)edge_mask)[gid] != 0);
    if (!m) return;
    int src = edge_index[(b * 2 + 0) * E_ + e];
    int tgt = edge_index[(b * 2 + 1) * E_ + e];
    if (src < 0 || src >= NN_ || tgt < 0 || tgt >= NN_) return;
    if (src == 0 && tgt == 0) return;

    float4 ef = edge_feat[gid];
    int c0 = (int)ef.x, c1 = (int)ef.y, c2 = (int)ef.z;
    float dist = ef.w;

    int r;
    if (c0 == 0 || c0 == 1) {
        r = min(max(c0 * 4 + c1 * 2 + c2, 0), 19);
    } else if (c0 == 5) {
        int pi = min(max(c1, 0), 14);
        int nl = nlig[b];
        bool sl = src < nl, tl = tgt < nl;
        int loc = (sl && tl) ? 0 : ((!sl && !tl) ? 1 : 2);
        r = 20 + loc * 15 + pi;
    } else r = 65;   // zero row

    // segment index: #{T[k] < dist}
    int lo = 0;
#pragma unroll
    for (int q = 0; q < 8; ++q) {
        float4 tv = *reinterpret_cast<const float4*>(T + 4 * q);
        lo += (tv.x < dist) ? 1 : 0;
        lo += (tv.y < dist) ? 1 : 0;
        lo += (tv.z < dist) ? 1 : 0;
        lo += (tv.w < dist) ? 1 : 0;
    }

    int s1 = src + 1, t1 = tgt + 1;
    int db = __float_as_int(dist);
    int base = (lo << 16) | (r << 9);
    int bin1 = b * N1_ + s1, bin2i = b * N1_ + t1;
    int p = atomicAdd(&counts[bin1], 1);
    if (p < CAP_) bins2[bin1 * CAP_ + p] = make_int2(base | t1, db);
    p = atomicAdd(&counts[bin2i], 1);
    if (p < CAP_) bins2[bin2i * CAP_ + p] = make_int2(base | s1, db);
}

// One block per (b, half, 5-row chunk); 512 threads = 8 waves; each WAVE owns
// 2 h-planes (wave-private LDS strip) -> no barriers in the row loop.
// LDS rows are SHIFTED: column t lives at (4-off)+t, off=(4-((h+i)&3))&3, so
// LDS float4 and global dwordx4 accesses are both 16B-aligned.
__global__ __launch_bounds__(512, 8) void chunk_kernel(
    const float* __restrict__ structural_w,   // (20,H)
    const float* __restrict__ plip_protein_w, // (15,H)
    const float* __restrict__ plip_ligand_w,  // (15,H)
    const float* __restrict__ plip_inter_w,   // (15,H)
    const float* __restrict__ loc_w,          // (4,H)
    const float* __restrict__ virtual_w,      // (1,H)
    const float* __restrict__ A,              // (33,32)
    const float* __restrict__ Bv,             // (33,32)
    const int*   __restrict__ counts,         // (NBIN_)
    const int2*  __restrict__ bins2,          // (NBIN_,CAP_)
    float* __restrict__ out)                  // (B,H,N1,N1)
{
    __shared__ float4 srow4[HH_ * (STRIDE_ / 4)];   // 25344 B; wave w owns rows 2w,2w+1
    __shared__ float sA[33 * TS_], sB[33 * TS_];    // 2772 B each
    __shared__ float sType[66 * TS_];               // 5544 B
    float* srow = reinterpret_cast<float*>(srow4);

    int bid = blockIdx.x;
    int chunk = bid % NCH_;
    int rest  = bid / NCH_;          // 0..31
    int half = rest & 1;
    int b = rest >> 1;
    int h0 = half << 4;
    int tid = threadIdx.x;
    int wv = tid >> 6, lane = tid & 63;

    int i0 = chunk * CHUNK_;
    int rowid0 = b * N1_ + i0;

    // prefetch all row counts (contiguous) before the staging barrier
    int cnts[CHUNK_];
#pragma unroll
    for (int ii = 0; ii < CHUNK_; ++ii) cnts[ii] = counts[rowid0 + ii];

    // ---- stage tables (once per block) ----
    for (int idx = tid; idx < 33 * 16; idx += 512) {
        int s = idx >> 4, hh = idx & 15;
        sA[s * TS_ + hh] = A[s * 32 + h0 + hh];
        sB[s * TS_ + hh] = Bv[s * 32 + h0 + hh];
    }
    for (int idx = tid; idx < 66 * 16; idx += 512) {
        int r = idx >> 4, hh = idx & 15;
        float v;
        if (r < 20) v = structural_w[r * 32 + h0 + hh];
        else if (r < 65) {
            int t2 = r - 20;
            int loc = t2 / 15, pi = t2 - loc * 15;
            const float* pw = (loc == 0) ? plip_ligand_w
                            : (loc == 1) ? plip_protein_w : plip_inter_w;
            v = pw[pi * 32 + h0 + hh] + loc_w[loc * 32 + h0 + hh];
        } else v = 0.0f;
        sType[r * TS_ + hh] = v;
    }

    int hh_q = lane & 1;             // plane within wave's pair
    int slot = lane >> 1;            // entry slot 0..31
    int hhg  = (wv << 1) | hh_q;     // hh within half, 0..15
    int hq   = h0 + hhg;             // global h for gather lane
    float* sW = srow + (wv << 1) * STRIDE_;   // wave-private strip (2 rows)

    int rw = lane >> 5;              // writeout: row 0..1 per 32-lane group
    int sl = lane & 31;
    int hw = h0 + (wv << 1) + rw;
    float vw0 = virtual_w[h0 + (wv << 1)];
    float vw1 = virtual_w[h0 + (wv << 1) + 1];

    __syncthreads();                 // the ONLY block barrier

#pragma unroll 1
    for (int ii = 0; ii < CHUNK_; ++ii) {
        int i = i0 + ii;
        int rowid = rowid0 + ii;

        // ---- init wave strip (2 rows) ----
#pragma unroll
        for (int r = 0; r < 2; ++r) {
            float vwr = (r == 0) ? vw0 : vw1;
            float fill = (i == 0) ? vwr : 0.0f;
            float4 f4 = make_float4(fill, fill, fill, fill);
            float4* rp = reinterpret_cast<float4*>(sW + r * STRIDE_);
            for (int c = lane; c < STRIDE_ / 4; c += 64) rp[c] = f4;
        }
        if (i != 0 && lane < 2) {    // virtual column t=0 (disjoint from scatter)
            int hr = h0 + (wv << 1) + lane;
            int off = (4 - ((hr + i) & 3)) & 3;
            sW[lane * STRIDE_ + 4 - off] = (lane == 0) ? vw0 : vw1;
        }

        // ---- gather (wave-private; no barrier) ----
        int cnt = cnts[ii]; cnt = cnt < CAP_ ? cnt : CAP_;
        int offq = (4 - ((hq + i) & 3)) & 3;
        int base = hh_q * STRIDE_ + 4 - offq;
        for (int j = slot; j < cnt; j += 32) {
            int2 e2 = bins2[rowid * CAP_ + j];
            float dist = __int_as_float(e2.y);
            int other = e2.x & 0x1FF;
            int r     = (e2.x >> 9) & 0x7F;
            int lo    = e2.x >> 16;
            float acc = fmaf(dist, sB[lo * TS_ + hhg], sA[lo * TS_ + hhg])
                      + sType[r * TS_ + hhg];
            atomicAdd(&sW[base + other], acc);
        }

        // ---- writeout (wave-private; per-wave LDS ordering) ----
        {
            const float* rr = sW + rw * STRIDE_;
            float* dst = out + ((size_t)(b * H_ + hw)) * PLANE_ + (size_t)i * N1_;
            int off = (4 - ((hw + i) & 3)) & 3;
            if (sl < off) dst[sl] = rr[4 - off + sl];
            int nvec = (N1_ - off) >> 2;            // 95 or 96
            for (int q = sl; q < nvec; q += 32) {   // 3 iterations
                float4 v = *reinterpret_cast<const float4*>(rr + 4 + 4 * q);
                *reinterpret_cast<float4*>(dst + off + 4 * q) = v;
            }
            int done = off + (nvec << 2);
            int rem = N1_ - done;                   // 0..3
            if (sl < rem) dst[done + sl] = rr[4 + 4 * nvec + sl];
        }
    }
}

// ============================================================================
// FALLBACK PATH (round-1, passing): used only if ws_size is too small.
// ============================================================================

__global__ __launch_bounds__(256) void init_out_kernel(
    float* __restrict__ out, const float* __restrict__ virtual_w)
{
    unsigned int tid = blockIdx.x * blockDim.x + threadIdx.x;
    unsigned int base = tid * 4u;
    if (base >= (unsigned int)TOTAL_) return;
    float4 v; float* pv = &v.x;
#pragma unroll
    for (int u = 0; u < 4; ++u) {
        unsigned int idx = base + u;
        unsigned int bh     = idx / (unsigned int)PLANE_;
        unsigned int within = idx - bh * (unsigned int)PLANE_;
        unsigned int h = bh & (H_ - 1);
        unsigned int i = within / (unsigned int)N1_;
        unsigned int j = within - i * (unsigned int)N1_;
        pv[u] = (i == 0u || j == 0u) ? virtual_w[h] : 0.0f;
    }
    *reinterpret_cast<float4*>(out + base) = v;
}

__global__ __launch_bounds__(256) void edge_kernel(
    const float4* __restrict__ edge_feat, const int* __restrict__ edge_index,
    const void* __restrict__ edge_mask, const int* __restrict__ nlig,
    const float* __restrict__ structural_w, const float* __restrict__ plip_protein_w,
    const float* __restrict__ plip_ligand_w, const float* __restrict__ plip_inter_w,
    const float* __restrict__ loc_w, const float* __restrict__ W1,
    const float* __restrict__ b1, const float* __restrict__ W2,
    const float* __restrict__ b2, float* __restrict__ out)
{
    __shared__ float sW2[H_ * H_];
    __shared__ float sW1[H_], sb1[H_], sb2[H_];
    __shared__ float sStruct[20 * H_];
    __shared__ float sPlipP[15 * H_], sPlipL[15 * H_], sPlipI[15 * H_];
    __shared__ float sLoc[4 * H_];

    for (int i = threadIdx.x; i < H_ * H_; i += blockDim.x) sW2[i] = W2[i];
    if (threadIdx.x < H_) {
        sW1[threadIdx.x] = W1[threadIdx.x];
        sb1[threadIdx.x] = b1[threadIdx.x];
        sb2[threadIdx.x] = b2[threadIdx.x];
    }
    for (int i = threadIdx.x; i < 20 * H_; i += blockDim.x) sStruct[i] = structural_w[i];
    for (int i = threadIdx.x; i < 15 * H_; i += blockDim.x) {
        sPlipP[i] = plip_protein_w[i]; sPlipL[i] = plip_ligand_w[i]; sPlipI[i] = plip_inter_w[i];
    }
    for (int i = threadIdx.x; i < 4 * H_; i += blockDim.x) sLoc[i] = loc_w[i];

    int lane = threadIdx.x & 63;
    int probe = ((const int*)edge_mask)[lane];
    bool byte_mask = __any(probe != 0 && probe != 1);
    __syncthreads();

    int gid = blockIdx.x * blockDim.x + threadIdx.x;
    int b = gid >> 13, e = gid & (E_ - 1);
    bool m = byte_mask ? (((const unsigned char*)edge_mask)[gid] != 0)
                       : (((const int*)edge_mask)[gid] != 0);
    if (!m) return;
    int src = edge_index[(b * 2 + 0) * E_ + e];
    int tgt = edge_index[(b * 2 + 1) * E_ + e];
    if (src < 0 || src >= NN_ || tgt < 0 || tgt >= NN_) return;
    if (src == 0 && tgt == 0) return;

    float4 ef = edge_feat[gid];
    int c0 = (int)ef.x, c1 = (int)ef.y, c2 = (int)ef.z;
    float dist = ef.w;
    const float* type_ptr = nullptr; const float* loc_ptr = nullptr;
    if (c0 == 0 || c0 == 1) {
        int si = min(max(c0 * 4 + c1 * 2 + c2, 0), 19);
        type_ptr = &sStruct[si * H_];
    } else if (c0 == 5) {
        int pi = min(max(c1, 0), 14);
        int nl = nlig[b];
        bool sl = src < nl, tl = tgt < nl;
        const float* pw; int loc;
        if (sl && tl)        { pw = sPlipL; loc = 0; }
        else if (!sl && !tl) { pw = sPlipP; loc = 1; }
        else                 { pw = sPlipI; loc = 2; }
        type_ptr = &pw[pi * H_]; loc_ptr = &sLoc[loc * H_];
    }
    float hk[H_];
#pragma unroll
    for (int k = 0; k < H_; ++k) {
        float v = fmaf(dist, sW1[k], sb1[k]);
        hk[k] = v > 0.0f ? v : 0.0f;
    }
    int s1 = src + 1, t1 = tgt + 1;
    float* outb = out + (size_t)b * H_ * PLANE_;
    int off1 = s1 * N1_ + t1, off2 = t1 * N1_ + s1;
#pragma unroll 4
    for (int h = 0; h < H_; ++h) {
        float acc = sb2[h];
#pragma unroll
        for (int k = 0; k < H_; ++k) acc = fmaf(hk[k], sW2[h * H_ + k], acc);
        if (type_ptr) acc += type_ptr[h];
        if (loc_ptr)  acc += loc_ptr[h];
        float* p = outb + (size_t)h * PLANE_;
        unsafeAtomicAdd(p + off1, acc);
        unsafeAtomicAdd(p + off2, acc);
    }
}

// ============================================================================
extern "C" void kernel_launch(void* const* d_in, const int* in_sizes, int n_in,
                              void* d_out, int out_size, void* d_ws, size_t ws_size,
                              hipStream_t stream)
{
    const float4* edge_feat      = (const float4*)d_in[0];
    const int*    edge_index     = (const int*)  d_in[2];
    const void*   edge_mask      =               d_in[3];
    const int*    nlig           = (const int*)  d_in[4];
    const float*  structural_w   = (const float*)d_in[5];
    const float*  plip_protein_w = (const float*)d_in[6];
    const float*  plip_ligand_w  = (const float*)d_in[7];
    const float*  plip_inter_w   = (const float*)d_in[8];
    const float*  loc_w          = (const float*)d_in[9];
    const float*  virtual_w      = (const float*)d_in[10];
    const float*  W1             = (const float*)d_in[11];
    const float*  b1             = (const float*)d_in[12];
    const float*  W2             = (const float*)d_in[13];
    const float*  b2             = (const float*)d_in[14];
    float* out = (float*)d_out;

    if (ws_size >= WS_NEED) {
        char* ws = (char*)d_ws;
        int*   counts = (int*)  (ws + WS_COUNTS);
        float* T      = (float*)(ws + WS_T);
        float* A      = (float*)(ws + WS_A);
        float* Bv     = (float*)(ws + WS_B);
        int2*  bins2  = (int2*) (ws + WS_BINS2);

        prep_kernel<<<25, 256, 0, stream>>>(W1, b1, W2, b2, T, A, Bv, counts);
        bin_kernel<<<(B_ * E_) / 256, 256, 0, stream>>>(
            edge_feat, edge_index, edge_mask, nlig, T, counts, bins2);
        chunk_kernel<<<B_ * 2 * NCH_, 512, 0, stream>>>(
            structural_w, plip_protein_w, plip_ligand_w, plip_inter_w,
            loc_w, virtual_w, A, Bv, counts, bins2, out);
    } else {
        unsigned int nth  = (unsigned int)(TOTAL_ / 4);
        unsigned int nblk = (nth + 255u) / 256u;
        init_out_kernel<<<nblk, 256, 0, stream>>>(out, virtual_w);
        edge_kernel<<<(B_ * E_) / 256, 256, 0, stream>>>(
            edge_feat, edge_index, edge_mask, nlig,
            structural_w, plip_protein_w, plip_ligand_w, plip_inter_w,
            loc_w, W1, b1, W2, b2, out);
    }
}